// Round 15
// baseline (150.097 us; speedup 1.0000x reference)
//
#include <hip/hip_runtime.h>
#include <cstdint>

#define NN 16000
#define KK 16
#define FIN 32
#define HH 64
#define NE (NN*KK)
#define GG 32                    // 15.6 pts/cell; 3x3 rect -> stop-radius lambda~49 >> 16
#define NCELL (GG*GG)

#define KNNB 250                 // knn blocks: 64 nodes/block (4 lanes/node) -- R12-proven
#define GEMM1B (NN*16/256)       // 1000 gemm1 blocks
#define NWAVE (KNNB*4)           // 1000 knn waves -> partial min/max slots

// ---------------------------------------------------------------- front: pack + histogram + scan + scatter (one dispatch)
// Replaces memset+prep+scatter (3 dispatches -> 1) with NO cross-block
// dependency: cellid is a pure function of c, so each block redundantly
// histograms ALL 16000 coords into LDS (single pass; elements before this
// block's range additionally counted into pre[] for the rank base). Then the
// R12-proven 256-thread scan gives lds_cs; rank = LDS-atomic on pre[cell]
// (bijective per cell; within-cell order was already nondeterministic in R12
// and is provably irrelevant: knn selection is exact-key with index
// tie-break). Block 0 publishes cstart for knn. Buffers cnt/cellid/pack and
// all global atomics eliminated.
__global__ __launch_bounds__(256) void front_kernel(const float* __restrict__ c,
                                                    unsigned* __restrict__ cstart,
                                                    float4* __restrict__ sorted,
                                                    int* __restrict__ sid) {
#pragma clang fp contract(off)
  __shared__ unsigned hist[NCELL];       // all-elements histogram (4 KB)
  __shared__ unsigned pre[NCELL];        // prefix-range histogram -> rank cursor
  __shared__ unsigned lds_cs[NCELL + 1];
  __shared__ unsigned wsum[4];
  const int tid = threadIdx.x;
  const int lane = tid & 63, wv = tid >> 6;
  const int start = blockIdx.x * 256;
  for (int j = tid; j < NCELL; j += 256) { hist[j] = 0u; pre[j] = 0u; }
  __syncthreads();

  // own element (pack values kept in registers; same ops as R12 prep)
  int i = start + tid;
  float xv = 0.f, yv = 0.f, sq = 0.f;
  unsigned cell_own = 0;
  bool valid = (i < NN);
  if (valid) {
    xv = c[2*i]; yv = c[2*i+1];
    float xx = xv * xv;          // round(x^2)  (no fma: contract off)
    float yy = yv * yv;          // round(y^2)
    sq = xx + yy;                // round(xx+yy)
    int cx = (int)(xv * GG); cx = cx > GG-1 ? GG-1 : (cx < 0 ? 0 : cx);
    int cy = (int)(yv * GG); cy = cy > GG-1 ? GG-1 : (cy < 0 ? 0 : cy);
    cell_own = (unsigned)(cy * GG + cx);
  }

  // single pass over all N: histogram-all + prefix-range histogram
  const float2* c2 = (const float2*)c;
  for (int j = tid; j < NN; j += 256) {
    float2 v = c2[j];
    int cx = (int)(v.x * GG); cx = cx > GG-1 ? GG-1 : (cx < 0 ? 0 : cx);
    int cy = (int)(v.y * GG); cy = cy > GG-1 ? GG-1 : (cy < 0 ? 0 : cy);
    unsigned cl = (unsigned)(cy * GG + cx);
    atomicAdd(&hist[cl], 1u);
    if (j < start) atomicAdd(&pre[cl], 1u);
  }
  __syncthreads();

  // scan hist -> lds_cs (R12-proven 256-thread code, 4 cells/thread)
  {
    unsigned h0 = hist[tid*4+0], h1 = hist[tid*4+1], h2 = hist[tid*4+2], h3 = hist[tid*4+3];
    unsigned s = h0 + h1 + h2 + h3;
    unsigned v = s;
#pragma unroll
    for (int off = 1; off < 64; off <<= 1) {
      unsigned u = __shfl_up(v, off, 64);
      if (lane >= off) v += u;
    }
    if (lane == 63) wsum[wv] = v;
    __syncthreads();
    if (wv == 0) {
      unsigned t = (lane < 4) ? wsum[lane] : 0u;
      unsigned vv = t;
#pragma unroll
      for (int off = 1; off < 4; off <<= 1) {
        unsigned u = __shfl_up(vv, off, 64);
        if (lane >= off) vv += u;
      }
      if (lane < 4) wsum[lane] = vv - t;           // exclusive
    }
    __syncthreads();
    unsigned b = wsum[wv] + v - s;
    lds_cs[tid*4+0] = b; b += h0;
    lds_cs[tid*4+1] = b; b += h1;
    lds_cs[tid*4+2] = b; b += h2;
    lds_cs[tid*4+3] = b; b += h3;
    if (tid == 255) lds_cs[NCELL] = b;             // == NN
    __syncthreads();
  }
  if (blockIdx.x == 0) {
    cstart[tid*4+0] = lds_cs[tid*4+0];
    cstart[tid*4+1] = lds_cs[tid*4+1];
    cstart[tid*4+2] = lds_cs[tid*4+2];
    cstart[tid*4+3] = lds_cs[tid*4+3];
    if (tid == 255) cstart[NCELL] = lds_cs[NCELL];
  }

  // rank + scatter own element (pre[cell] = base count; atomic gives order)
  if (valid) {
    unsigned r = atomicAdd(&pre[cell_own], 1u);
    unsigned p = lds_cs[cell_own] + r;
    sorted[p] = make_float4(xv, yv, sq, __uint_as_float((unsigned)i));
    sid[p] = i;
  }
}

// ---------------------------------------------------------------- knn (R12 body) + gemm1 backfill
// R12-proven: atomic-free epilogue (wave min/max -> plain store to part[]).
__global__ __launch_bounds__(256) void knn_gemm1_kernel(const float4* __restrict__ sorted,
                                                        const unsigned* __restrict__ cstart,
                                                        const float* __restrict__ c,
                                                        int* __restrict__ nbr,
                                                        float* __restrict__ de,
                                                        uint2* __restrict__ part,
                                                        const float* __restrict__ xa_,
                                                        const float* __restrict__ w1,
                                                        float* __restrict__ xw1) {
#pragma clang fp contract(off)
  if (blockIdx.x >= KNNB) {
    // ---- gemm1: xw1 = x @ W1, KIN=32, 4 features/thread (R1-verbatim, proven)
    int gid = (blockIdx.x - KNNB) * 256 + threadIdx.x;   // NN*16 total
    int i = gid >> 4, fq = gid & 15;
    const float4* ar = (const float4*)(xa_ + i * FIN);
    float4 A[FIN/4];
#pragma unroll
    for (int qq = 0; qq < FIN/4; ++qq) A[qq] = ar[qq];
    float4 acc = make_float4(0.f, 0.f, 0.f, 0.f);
#pragma unroll
    for (int k = 0; k < FIN; ++k) {
      float av = ((const float*)A)[k];
      float4 wv4 = *(const float4*)(w1 + k*HH + 4*fq);
      acc.x = fmaf(av, wv4.x, acc.x);
      acc.y = fmaf(av, wv4.y, acc.y);
      acc.z = fmaf(av, wv4.z, acc.z);
      acc.w = fmaf(av, wv4.w, acc.w);
    }
    *(float4*)(xw1 + i*HH + 4*fq) = acc;
    return;
  }

  const int g = blockIdx.x * 256 + threadIdx.x;
  const int t = g >> 2;                            // sorted node index
  const int q = g & 3;                             // quad lane
  const int lane = threadIdx.x & 63;
  const float4 me = sorted[t];
  const int myid = (int)__float_as_uint(me.w);
  const float h = 1.0f / GG;                       // exact 2^-5
  int cx = (int)(me.x * GG); cx = cx > GG-1 ? GG-1 : (cx < 0 ? 0 : cx);
  int cy = (int)(me.y * GG); cy = cy > GG-1 ? GG-1 : (cy < 0 ? 0 : cy);

  unsigned long long kd[KK];
#pragma unroll
  for (int m = 0; m < KK; ++m) kd[m] = ~0ull;

  auto process = [&](float4 cand) {
    int j = (int)__float_as_uint(cand.w);
    float xprod = me.x * cand.x;                       // round(x_i*x_j)
    float dot   = __builtin_fmaf(me.y, cand.y, xprod); // BLAS K=2 fma
    float S     = me.z + cand.z;                       // round(sq_i+sq_j)
    float twod  = dot + dot;                           // exact *2
    float d2    = S - twod;                            // one rounding
    unsigned ub = __float_as_uint(d2);
    ub = (ub & 0x80000000u) ? ~ub : (ub | 0x80000000u);
    unsigned long long key = ((unsigned long long)ub << 32) | (unsigned)j;
    if (j != myid && key < kd[KK-1]) {
      unsigned long long ck = key;
#pragma unroll
      for (int m = 0; m < KK; ++m) {
        bool sw = ck < kd[m];
        unsigned long long lo = sw ? ck : kd[m];
        unsigned long long hi = sw ? kd[m] : ck;
        kd[m] = lo; ck = hi;
      }
    }
  };
  // 2-deep pipelined span scan; instantiated at exactly 3 call sites
  auto scanSpan = [&](unsigned p0, unsigned p1) {
    unsigned pp = p0 + (unsigned)q;
    if (pp >= p1) return;
    float4 cur = sorted[pp];
    unsigned pn = pp + 4;
#pragma unroll 1
    while (pn < p1) {
      float4 nxt = sorted[pn];
      process(cur);
      cur = nxt;
      pn += 4;
    }
    process(cur);
  };

  // ---- initial 3x3 rect (site 1): row bounds software-pipelined
  int lxa = cx-1 < 0 ? 0 : cx-1;
  int lxb = cx+1 > GG-1 ? GG-1 : cx+1;
  int lya = cy-1 < 0 ? 0 : cy-1;
  int lyb = cy+1 > GG-1 ? GG-1 : cy+1;
  {
    unsigned b0 = cstart[lya*GG + lxa];
    unsigned b1 = cstart[lya*GG + lxb + 1];
#pragma unroll 1
    for (int y = lya; y <= lyb; ++y) {
      unsigned n0 = 0, n1 = 0;
      if (y < lyb) { n0 = cstart[(y+1)*GG + lxa]; n1 = cstart[(y+1)*GG + lxb + 1]; }
      scanSpan(b0, b1);
      b0 = n0; b1 = n1;
    }
  }

  // ---- ring expansion with exact count-based stop (validated; generic in h)
  int R = 1;
  while (true) {
    bool whole = (lxa <= 0) && (lxb >= GG-1) && (lya <= 0) && (lyb >= GG-1);
    bool done = whole;
    if (!done) {
      float edge = 1e30f;
      if (lxa > 0)    edge = fminf(edge, me.x - (float)lxa * h);
      if (lxb < GG-1) edge = fminf(edge, (float)(lxb+1) * h - me.x);
      if (lya > 0)    edge = fminf(edge, me.y - (float)lya * h);
      if (lyb < GG-1) edge = fminf(edge, (float)(lyb+1) * h - me.y);
      float lim = edge * edge - 1e-5f;             // margin >> Gram noise (~1e-6)
      if (lim > 0.0f) {
        unsigned lb = __float_as_uint(lim) | 0x80000000u;   // map(lim), lim>0
        int cle = 0;
#pragma unroll
        for (int m = 0; m < KK; ++m) cle += ((unsigned)(kd[m] >> 32) <= lb) ? 1 : 0;
        cle += __shfl_xor(cle, 1, 64);
        cle += __shfl_xor(cle, 2, 64);
        done = cle >= KK;
      }
    }
    if (done) break;
    ++R;
    int nxa = cx-R < 0 ? 0 : cx-R;
    int nxb = cx+R > GG-1 ? GG-1 : cx+R;
    int nya = cy-R < 0 ? 0 : cy-R;
    int nyb = cy+R > GG-1 ? GG-1 : cy+R;
    // new top/bottom rows (site 2)
#pragma unroll 1
    for (int rr = 0; rr < 2; ++rr) {
      int y = rr ? nyb : nya;
      bool has = rr ? (nyb > lyb) : (nya < lya);
      if (has) {
        unsigned p0 = cstart[y*GG + nxa];
        unsigned p1 = cstart[y*GG + nxb + 1];
        scanSpan(p0, p1);
      }
    }
    // new left/right columns (site 3): per-cell spans, bounds pipelined
#pragma unroll 1
    for (int ss = 0; ss < 2; ++ss) {
      int xcol = ss ? nxb : nxa;
      bool has = ss ? (nxb > lxb) : (nxa < lxa);
      if (has) {
        unsigned b0 = cstart[lya*GG + xcol];
        unsigned b1 = cstart[lya*GG + xcol + 1];
#pragma unroll 1
        for (int y = lya; y <= lyb; ++y) {
          unsigned n0 = 0, n1 = 0;
          if (y < lyb) { n0 = cstart[(y+1)*GG + xcol]; n1 = cstart[(y+1)*GG + xcol + 1]; }
          scanSpan(b0, b1);
          b0 = n0; b1 = n1;
        }
      }
    }
    lxa = nxa; lxb = nxb; lya = nya; lyb = nyb;
  }

  // ---- merge 4 sorted per-lane lists -> global top-16 (keys unique via j bits)
  unsigned res[4];
#pragma unroll 1
  for (int r = 0; r < KK; ++r) {
    unsigned long long md = kd[0];
    unsigned long long m1 = __shfl_xor(md, 1, 64); md = m1 < md ? m1 : md;
    unsigned long long m2 = __shfl_xor(md, 2, 64); md = m2 < md ? m2 : md;
    if (kd[0] == md) {                              // unique winner lane pops
#pragma unroll
      for (int m = 0; m < KK-1; ++m) kd[m] = kd[m+1];
      kd[KK-1] = ~0ull;
    }
    if ((r >> 2) == q) res[r & 3] = (unsigned)(md & 0xFFFFFFFFull);
  }

  // ---- write nbr + edge epilogue; wave min/max -> plain store (NO atomics)
  int4 w4; w4.x = (int)res[0]; w4.y = (int)res[1]; w4.z = (int)res[2]; w4.w = (int)res[3];
  *(int4*)(nbr + myid*KK + 4*q) = w4;
  unsigned bmin = 0xFFFFFFFFu, bmax = 0u;
#pragma unroll
  for (int e = 0; e < 4; ++e) {
    int j = (int)res[e];
    float dx = me.x - c[2*j];
    float dy = me.y - c[2*j+1];
    float xx = dx * dx;
    float yy = dy * dy;
    float d  = __builtin_sqrtf(xx + yy);
    de[myid*KK + 4*q + e] = d;
    unsigned bb = __float_as_uint(d);               // d >= 0: bit order == float order
    bmin = bmin < bb ? bmin : bb;
    bmax = bmax > bb ? bmax : bb;
  }
#pragma unroll
  for (int off = 32; off > 0; off >>= 1) {
    unsigned ob = __shfl_xor(bmin, off, 64);
    bmin = bmin < ob ? bmin : ob;
    unsigned oB = __shfl_xor(bmax, off, 64);
    bmax = bmax > oB ? bmax : oB;
  }
  if (lane == 0) part[g >> 6] = make_uint2(bmin, bmax);   // wave id in [0,1000)
}

// ---------------------------------------------------------------- ew + deg + dis (+ partial min/max reduce)
// Every block redundantly reduces the 1000-entry partial array (8 KB, L2-hot)
// with integer min/max -> mx/rng bit-identical to the old gmm atomics.
__global__ __launch_bounds__(256) void ewdeg_kernel(const uint2* __restrict__ part,
                                                    float* __restrict__ de,   // in: d, out: ew
                                                    float* __restrict__ dis) {
#pragma clang fp contract(off)
  __shared__ unsigned smn[4], smx[4];
  const int tid = threadIdx.x;
  const int lane = tid & 63, wv = tid >> 6;
  unsigned mn = 0xFFFFFFFFu, mxb = 0u;
  for (int j = tid; j < NWAVE; j += 256) {
    uint2 p = part[j];
    mn  = mn  < p.x ? mn  : p.x;
    mxb = mxb > p.y ? mxb : p.y;
  }
#pragma unroll
  for (int off = 32; off > 0; off >>= 1) {
    unsigned om = __shfl_xor(mn, off, 64);
    mn = mn < om ? mn : om;
    unsigned ox = __shfl_xor(mxb, off, 64);
    mxb = mxb > ox ? mxb : ox;
  }
  if (lane == 0) { smn[wv] = mn; smx[wv] = mxb; }
  __syncthreads();
  mn  = smn[0]; mxb = smx[0];
#pragma unroll
  for (int k = 1; k < 4; ++k) {
    mn  = mn  < smn[k] ? mn  : smn[k];
    mxb = mxb > smx[k] ? mxb : smx[k];
  }

  int i = blockIdx.x * 256 + tid;
  if (i >= NN) return;
  float mx  = __uint_as_float(mxb);
  float rng = mx - __uint_as_float(mn);
  float deg = 0.0f;                         // edges first, self-loop last (segment_sum order)
  float4* dp = (float4*)(de + i*KK);
#pragma unroll
  for (int qq = 0; qq < 4; ++qq) {
    float4 v = dp[qq];
    float e0 = (mx - v.x) / rng;
    float e1 = (mx - v.y) / rng;
    float e2 = (mx - v.z) / rng;
    float e3 = (mx - v.w) / rng;
    deg = deg + e0; deg = deg + e1;
    deg = deg + e2; deg = deg + e3;
    dp[qq] = make_float4(e0, e1, e2, e3);
  }
  deg = deg + 1.0f;                         // self-loop weight 1, added last
  dis[i] = 1.0f / __builtin_sqrtf(deg);     // deg >= 1
}

// ---------------------------------------------------------------- agg1 + relu + gemm2 fused (R12-verbatim)
__global__ __launch_bounds__(256) void agg_gemm2_kernel(const float* __restrict__ xw,
                                                        const int* __restrict__ nbr,
                                                        const float* __restrict__ ew,
                                                        const float* __restrict__ dis,
                                                        const float* __restrict__ b,
                                                        const int* __restrict__ sid,
                                                        const float* __restrict__ w2,
                                                        float* __restrict__ xw2) {
  int wv = threadIdx.x >> 6, lane = threadIdx.x & 63;
  int i = sid[(blockIdx.x << 2) + wv];
  float di = dis[i];
  float acc = 0.0f;
#pragma unroll 4
  for (int k = 0; k < KK; ++k) {
    int s = nbr[i*KK + k];
    float coef = (dis[s] * ew[i*KK + k]) * di;   // (dis[s]*w)*dis[t]
    acc = fmaf(coef, xw[s*HH + lane], acc);
  }
  acc = fmaf(di * di, xw[i*HH + lane], acc);     // self loop last
  float hv = fmaxf(acc + b[lane], 0.0f);         // h1[i][lane]
  float acc2 = 0.0f;
#pragma unroll 16
  for (int k = 0; k < HH; ++k) {
    float hk = __shfl(hv, k, 64);
    acc2 = fmaf(hk, w2[k*HH + lane], acc2);
  }
  xw2[i*HH + lane] = acc2;
}

// ---------------------------------------------------------------- agg2 + relu + fc (final, R12-verbatim)
__global__ __launch_bounds__(256) void agg_fc_kernel(const float* __restrict__ xw,
                                                     const int* __restrict__ nbr,
                                                     const float* __restrict__ ew,
                                                     const float* __restrict__ dis,
                                                     const float* __restrict__ b,
                                                     const float* __restrict__ wfc,
                                                     const float* __restrict__ bfc,
                                                     const int* __restrict__ sid,
                                                     float* __restrict__ out) {
  int wv = threadIdx.x >> 6, lane = threadIdx.x & 63;
  int i = sid[(blockIdx.x << 2) + wv];
  float di = dis[i];
  float acc = 0.0f;
#pragma unroll 4
  for (int k = 0; k < KK; ++k) {
    int s = nbr[i*KK + k];
    float coef = (dis[s] * ew[i*KK + k]) * di;
    acc = fmaf(coef, xw[s*HH + lane], acc);
  }
  acc = fmaf(di * di, xw[i*HH + lane], acc);
  float v = fmaxf(acc + b[lane], 0.0f);             // h2 feature
  float p = v * wfc[lane];                          // h2 @ Wfc  (F_OUT = 1)
#pragma unroll
  for (int off = 32; off > 0; off >>= 1) p = p + __shfl_xor(p, off, 64);
  if (lane == 0) out[i] = p + bfc[0];
}

// ---------------------------------------------------------------- launch (5 dispatches, no memset)
extern "C" void kernel_launch(void* const* d_in, const int* in_sizes, int n_in,
                              void* d_out, int out_size, void* d_ws, size_t ws_size,
                              hipStream_t stream) {
  (void)in_sizes; (void)n_in; (void)out_size; (void)ws_size;
  const float* x   = (const float*)d_in[0];
  const float* c   = (const float*)d_in[1];
  const float* W1  = (const float*)d_in[2];
  const float* b1  = (const float*)d_in[3];
  const float* W2  = (const float*)d_in[4];
  const float* b2  = (const float*)d_in[5];
  const float* Wfc = (const float*)d_in[6];
  const float* bfc = (const float*)d_in[7];
  float* out = (float*)d_out;

  char* ws = (char*)d_ws;
  size_t off = 0;
  auto alloc = [&](size_t bytes) -> void* {
    void* p = ws + off;
    off += (bytes + 255) & ~size_t(255);
    return p;
  };
  float4*   sorted = (float4*)  alloc(NN * sizeof(float4));       // 256 KB
  unsigned* cstart = (unsigned*)alloc((NCELL+1) * sizeof(unsigned));
  int*      sid    = (int*)     alloc(NN * sizeof(int));          // 64 KB
  int*      nbr    = (int*)     alloc(NE * sizeof(int));          // 1 MB
  float*    ew     = (float*)   alloc(NE * sizeof(float));        // 1 MB (d then ew in-place)
  float*    dis    = (float*)   alloc(NN * sizeof(float));        // 64 KB
  uint2*    part   = (uint2*)   alloc(NWAVE * sizeof(uint2));     // 8 KB wave partials
  float*    xw1    = (float*)   alloc(NN * HH * sizeof(float));   // 4 MB
  float*    xw2    = (float*)   alloc(NN * HH * sizeof(float));   // 4 MB

  const int NB = (NN + 255) / 256;
  front_kernel     <<<NB,   256, 0, stream>>>(c, cstart, sorted, sid);
  knn_gemm1_kernel <<<KNNB + GEMM1B, 256, 0, stream>>>(sorted, cstart, c, nbr, ew, part,
                                                       x, W1, xw1);
  ewdeg_kernel     <<<NB,   256, 0, stream>>>(part, ew, dis);
  agg_gemm2_kernel <<<NN/4, 256, 0, stream>>>(xw1, nbr, ew, dis, b1, sid, W2, xw2);
  agg_fc_kernel    <<<NN/4, 256, 0, stream>>>(xw2, nbr, ew, dis, b2, Wfc, bfc, sid, out);
}

// Round 16
// 138.227 us; speedup vs baseline: 1.0859x; 1.0859x over previous
//
#include <hip/hip_runtime.h>
#include <cstdint>

#define NN 16000
#define KK 16
#define FIN 32
#define HH 64
#define NE (NN*KK)
#define GG 32                    // 15.6 pts/cell; 3x3 rect -> stop-radius lambda~49 >> 16
#define NCELL (GG*GG)

#define KNNB 250                 // knn blocks: 64 nodes/block (4 lanes/node) -- R12-proven
#define GEMM1B (NN*16/256)       // 1000 gemm1 blocks
#define NWAVE (KNNB*4)           // 1000 knn waves -> partial min/max slots

// ---------------------------------------------------------------- prep + count
// rank packed into cellid: cell in bits[9:0], rank in bits[31:10] (rank<16000)
__global__ __launch_bounds__(256) void prep_count_kernel(const float* __restrict__ c,
                                                         float4* __restrict__ pack,
                                                         unsigned* __restrict__ cellid,
                                                         unsigned* __restrict__ cnt) {
#pragma clang fp contract(off)
  int i = blockIdx.x * 256 + threadIdx.x;
  if (i >= NN) return;
  float xv = c[2*i], yv = c[2*i+1];
  float xx = xv * xv;            // round(x^2)  (no fma: contract off)
  float yy = yv * yv;            // round(y^2)
  float sq = xx + yy;            // round(xx+yy)
  pack[i] = make_float4(xv, yv, sq, __uint_as_float((unsigned)i));
  int cx = (int)(xv * GG); cx = cx > GG-1 ? GG-1 : (cx < 0 ? 0 : cx);
  int cy = (int)(yv * GG); cy = cy > GG-1 ? GG-1 : (cy < 0 ? 0 : cy);
  unsigned cell = (unsigned)(cy * GG + cx);
  unsigned rank = atomicAdd(&cnt[cell], 1u);
  cellid[i] = cell | (rank << 10);
}

// ---------------------------------------------------------------- scatter (atomic-free) + redundant LDS scan
// Each block scans the 1024-cell histogram into LDS (R8-phase-B-proven code);
// block 0 also publishes cstart for knn. Position = cs[cell] + rank.
__global__ __launch_bounds__(256) void scatter_kernel(const float4* __restrict__ pack,
                                                      const unsigned* __restrict__ cellid,
                                                      const unsigned* __restrict__ cnt,
                                                      unsigned* __restrict__ cstart,
                                                      float4* __restrict__ sorted,
                                                      int* __restrict__ sid) {
  __shared__ unsigned lds_cs[NCELL + 1];
  __shared__ unsigned wsum[4];
  const int tid = threadIdx.x;
  const int lane = tid & 63, wv = tid >> 6;
  {
    unsigned h0 = cnt[tid*4+0], h1 = cnt[tid*4+1], h2 = cnt[tid*4+2], h3 = cnt[tid*4+3];
    unsigned s = h0 + h1 + h2 + h3;
    unsigned v = s;
#pragma unroll
    for (int off = 1; off < 64; off <<= 1) {
      unsigned u = __shfl_up(v, off, 64);
      if (lane >= off) v += u;
    }
    if (lane == 63) wsum[wv] = v;
    __syncthreads();
    if (wv == 0) {
      unsigned t = (lane < 4) ? wsum[lane] : 0u;
      unsigned vv = t;
#pragma unroll
      for (int off = 1; off < 4; off <<= 1) {
        unsigned u = __shfl_up(vv, off, 64);
        if (lane >= off) vv += u;
      }
      if (lane < 4) wsum[lane] = vv - t;           // exclusive
    }
    __syncthreads();
    unsigned b = wsum[wv] + v - s;
    lds_cs[tid*4+0] = b; b += h0;
    lds_cs[tid*4+1] = b; b += h1;
    lds_cs[tid*4+2] = b; b += h2;
    lds_cs[tid*4+3] = b; b += h3;
    if (tid == 255) lds_cs[NCELL] = b;             // == NN
    __syncthreads();
    if (blockIdx.x == 0) {
      cstart[tid*4+0] = lds_cs[tid*4+0];
      cstart[tid*4+1] = lds_cs[tid*4+1];
      cstart[tid*4+2] = lds_cs[tid*4+2];
      cstart[tid*4+3] = lds_cs[tid*4+3];
      if (tid == 255) cstart[NCELL] = lds_cs[NCELL];
    }
  }
  int i = blockIdx.x * 256 + tid;
  if (i >= NN) return;
  unsigned cc = cellid[i];
  unsigned p = lds_cs[cc & 1023u] + (cc >> 10);
  sorted[p] = pack[i];                             // .w carries original index bits
  sid[p] = i;
}

// ---------------------------------------------------------------- knn (R12 body) + gemm1 backfill
// R12-proven: atomic-free epilogue (wave min/max -> plain store to part[]).
__global__ __launch_bounds__(256) void knn_gemm1_kernel(const float4* __restrict__ sorted,
                                                        const unsigned* __restrict__ cstart,
                                                        const float* __restrict__ c,
                                                        int* __restrict__ nbr,
                                                        float* __restrict__ de,
                                                        uint2* __restrict__ part,
                                                        const float* __restrict__ xa_,
                                                        const float* __restrict__ w1,
                                                        float* __restrict__ xw1) {
#pragma clang fp contract(off)
  if (blockIdx.x >= KNNB) {
    // ---- gemm1: xw1 = x @ W1, KIN=32, 4 features/thread (R1-verbatim, proven)
    int gid = (blockIdx.x - KNNB) * 256 + threadIdx.x;   // NN*16 total
    int i = gid >> 4, fq = gid & 15;
    const float4* ar = (const float4*)(xa_ + i * FIN);
    float4 A[FIN/4];
#pragma unroll
    for (int qq = 0; qq < FIN/4; ++qq) A[qq] = ar[qq];
    float4 acc = make_float4(0.f, 0.f, 0.f, 0.f);
#pragma unroll
    for (int k = 0; k < FIN; ++k) {
      float av = ((const float*)A)[k];
      float4 wv4 = *(const float4*)(w1 + k*HH + 4*fq);
      acc.x = fmaf(av, wv4.x, acc.x);
      acc.y = fmaf(av, wv4.y, acc.y);
      acc.z = fmaf(av, wv4.z, acc.z);
      acc.w = fmaf(av, wv4.w, acc.w);
    }
    *(float4*)(xw1 + i*HH + 4*fq) = acc;
    return;
  }

  const int g = blockIdx.x * 256 + threadIdx.x;
  const int t = g >> 2;                            // sorted node index
  const int q = g & 3;                             // quad lane
  const int lane = threadIdx.x & 63;
  const float4 me = sorted[t];
  const int myid = (int)__float_as_uint(me.w);
  const float h = 1.0f / GG;                       // exact 2^-5
  int cx = (int)(me.x * GG); cx = cx > GG-1 ? GG-1 : (cx < 0 ? 0 : cx);
  int cy = (int)(me.y * GG); cy = cy > GG-1 ? GG-1 : (cy < 0 ? 0 : cy);

  unsigned long long kd[KK];
#pragma unroll
  for (int m = 0; m < KK; ++m) kd[m] = ~0ull;

  auto process = [&](float4 cand) {
    int j = (int)__float_as_uint(cand.w);
    float xprod = me.x * cand.x;                       // round(x_i*x_j)
    float dot   = __builtin_fmaf(me.y, cand.y, xprod); // BLAS K=2 fma
    float S     = me.z + cand.z;                       // round(sq_i+sq_j)
    float twod  = dot + dot;                           // exact *2
    float d2    = S - twod;                            // one rounding
    unsigned ub = __float_as_uint(d2);
    ub = (ub & 0x80000000u) ? ~ub : (ub | 0x80000000u);
    unsigned long long key = ((unsigned long long)ub << 32) | (unsigned)j;
    if (j != myid && key < kd[KK-1]) {
      unsigned long long ck = key;
#pragma unroll
      for (int m = 0; m < KK; ++m) {
        bool sw = ck < kd[m];
        unsigned long long lo = sw ? ck : kd[m];
        unsigned long long hi = sw ? kd[m] : ck;
        kd[m] = lo; ck = hi;
      }
    }
  };
  // 2-deep pipelined span scan; instantiated at exactly 3 call sites
  auto scanSpan = [&](unsigned p0, unsigned p1) {
    unsigned pp = p0 + (unsigned)q;
    if (pp >= p1) return;
    float4 cur = sorted[pp];
    unsigned pn = pp + 4;
#pragma unroll 1
    while (pn < p1) {
      float4 nxt = sorted[pn];
      process(cur);
      cur = nxt;
      pn += 4;
    }
    process(cur);
  };

  // ---- initial 3x3 rect (site 1): row bounds software-pipelined
  int lxa = cx-1 < 0 ? 0 : cx-1;
  int lxb = cx+1 > GG-1 ? GG-1 : cx+1;
  int lya = cy-1 < 0 ? 0 : cy-1;
  int lyb = cy+1 > GG-1 ? GG-1 : cy+1;
  {
    unsigned b0 = cstart[lya*GG + lxa];
    unsigned b1 = cstart[lya*GG + lxb + 1];
#pragma unroll 1
    for (int y = lya; y <= lyb; ++y) {
      unsigned n0 = 0, n1 = 0;
      if (y < lyb) { n0 = cstart[(y+1)*GG + lxa]; n1 = cstart[(y+1)*GG + lxb + 1]; }
      scanSpan(b0, b1);
      b0 = n0; b1 = n1;
    }
  }

  // ---- ring expansion with exact count-based stop (validated; generic in h)
  int R = 1;
  while (true) {
    bool whole = (lxa <= 0) && (lxb >= GG-1) && (lya <= 0) && (lyb >= GG-1);
    bool done = whole;
    if (!done) {
      float edge = 1e30f;
      if (lxa > 0)    edge = fminf(edge, me.x - (float)lxa * h);
      if (lxb < GG-1) edge = fminf(edge, (float)(lxb+1) * h - me.x);
      if (lya > 0)    edge = fminf(edge, me.y - (float)lya * h);
      if (lyb < GG-1) edge = fminf(edge, (float)(lyb+1) * h - me.y);
      float lim = edge * edge - 1e-5f;             // margin >> Gram noise (~1e-6)
      if (lim > 0.0f) {
        unsigned lb = __float_as_uint(lim) | 0x80000000u;   // map(lim), lim>0
        int cle = 0;
#pragma unroll
        for (int m = 0; m < KK; ++m) cle += ((unsigned)(kd[m] >> 32) <= lb) ? 1 : 0;
        cle += __shfl_xor(cle, 1, 64);
        cle += __shfl_xor(cle, 2, 64);
        done = cle >= KK;
      }
    }
    if (done) break;
    ++R;
    int nxa = cx-R < 0 ? 0 : cx-R;
    int nxb = cx+R > GG-1 ? GG-1 : cx+R;
    int nya = cy-R < 0 ? 0 : cy-R;
    int nyb = cy+R > GG-1 ? GG-1 : cy+R;
    // new top/bottom rows (site 2)
#pragma unroll 1
    for (int rr = 0; rr < 2; ++rr) {
      int y = rr ? nyb : nya;
      bool has = rr ? (nyb > lyb) : (nya < lya);
      if (has) {
        unsigned p0 = cstart[y*GG + nxa];
        unsigned p1 = cstart[y*GG + nxb + 1];
        scanSpan(p0, p1);
      }
    }
    // new left/right columns (site 3): per-cell spans, bounds pipelined
#pragma unroll 1
    for (int ss = 0; ss < 2; ++ss) {
      int xcol = ss ? nxb : nxa;
      bool has = ss ? (nxb > lxb) : (nxa < lxa);
      if (has) {
        unsigned b0 = cstart[lya*GG + xcol];
        unsigned b1 = cstart[lya*GG + xcol + 1];
#pragma unroll 1
        for (int y = lya; y <= lyb; ++y) {
          unsigned n0 = 0, n1 = 0;
          if (y < lyb) { n0 = cstart[(y+1)*GG + xcol]; n1 = cstart[(y+1)*GG + xcol + 1]; }
          scanSpan(b0, b1);
          b0 = n0; b1 = n1;
        }
      }
    }
    lxa = nxa; lxb = nxb; lya = nya; lyb = nyb;
  }

  // ---- merge 4 sorted per-lane lists -> global top-16 (keys unique via j bits)
  unsigned res[4];
#pragma unroll 1
  for (int r = 0; r < KK; ++r) {
    unsigned long long md = kd[0];
    unsigned long long m1 = __shfl_xor(md, 1, 64); md = m1 < md ? m1 : md;
    unsigned long long m2 = __shfl_xor(md, 2, 64); md = m2 < md ? m2 : md;
    if (kd[0] == md) {                              // unique winner lane pops
#pragma unroll
      for (int m = 0; m < KK-1; ++m) kd[m] = kd[m+1];
      kd[KK-1] = ~0ull;
    }
    if ((r >> 2) == q) res[r & 3] = (unsigned)(md & 0xFFFFFFFFull);
  }

  // ---- write nbr + edge epilogue; wave min/max -> plain store (NO atomics)
  int4 w4; w4.x = (int)res[0]; w4.y = (int)res[1]; w4.z = (int)res[2]; w4.w = (int)res[3];
  *(int4*)(nbr + myid*KK + 4*q) = w4;
  unsigned bmin = 0xFFFFFFFFu, bmax = 0u;
#pragma unroll
  for (int e = 0; e < 4; ++e) {
    int j = (int)res[e];
    float dx = me.x - c[2*j];
    float dy = me.y - c[2*j+1];
    float xx = dx * dx;
    float yy = dy * dy;
    float d  = __builtin_sqrtf(xx + yy);
    de[myid*KK + 4*q + e] = d;
    unsigned bb = __float_as_uint(d);               // d >= 0: bit order == float order
    bmin = bmin < bb ? bmin : bb;
    bmax = bmax > bb ? bmax : bb;
  }
#pragma unroll
  for (int off = 32; off > 0; off >>= 1) {
    unsigned ob = __shfl_xor(bmin, off, 64);
    bmin = bmin < ob ? bmin : ob;
    unsigned oB = __shfl_xor(bmax, off, 64);
    bmax = bmax > oB ? bmax : oB;
  }
  if (lane == 0) part[g >> 6] = make_uint2(bmin, bmax);   // wave id in [0,1000)
}

// ---------------------------------------------------------------- ew + deg + dis (+ partial min/max reduce)
// Every block redundantly reduces the 1000-entry partial array (8 KB, L2-hot)
// with integer min/max -> mx/rng bit-identical to the old gmm atomics.
__global__ __launch_bounds__(256) void ewdeg_kernel(const uint2* __restrict__ part,
                                                    float* __restrict__ de,   // in: d, out: ew
                                                    float* __restrict__ dis) {
#pragma clang fp contract(off)
  __shared__ unsigned smn[4], smx[4];
  const int tid = threadIdx.x;
  const int lane = tid & 63, wv = tid >> 6;
  unsigned mn = 0xFFFFFFFFu, mxb = 0u;
  for (int j = tid; j < NWAVE; j += 256) {
    uint2 p = part[j];
    mn  = mn  < p.x ? mn  : p.x;
    mxb = mxb > p.y ? mxb : p.y;
  }
#pragma unroll
  for (int off = 32; off > 0; off >>= 1) {
    unsigned om = __shfl_xor(mn, off, 64);
    mn = mn < om ? mn : om;
    unsigned ox = __shfl_xor(mxb, off, 64);
    mxb = mxb > ox ? mxb : ox;
  }
  if (lane == 0) { smn[wv] = mn; smx[wv] = mxb; }
  __syncthreads();
  mn  = smn[0]; mxb = smx[0];
#pragma unroll
  for (int k = 1; k < 4; ++k) {
    mn  = mn  < smn[k] ? mn  : smn[k];
    mxb = mxb > smx[k] ? mxb : smx[k];
  }

  int i = blockIdx.x * 256 + tid;
  if (i >= NN) return;
  float mx  = __uint_as_float(mxb);
  float rng = mx - __uint_as_float(mn);
  float deg = 0.0f;                         // edges first, self-loop last (segment_sum order)
  float4* dp = (float4*)(de + i*KK);
#pragma unroll
  for (int qq = 0; qq < 4; ++qq) {
    float4 v = dp[qq];
    float e0 = (mx - v.x) / rng;
    float e1 = (mx - v.y) / rng;
    float e2 = (mx - v.z) / rng;
    float e3 = (mx - v.w) / rng;
    deg = deg + e0; deg = deg + e1;
    deg = deg + e2; deg = deg + e3;
    dp[qq] = make_float4(e0, e1, e2, e3);
  }
  deg = deg + 1.0f;                         // self-loop weight 1, added last
  dis[i] = 1.0f / __builtin_sqrtf(deg);     // deg >= 1
}

// ---------------------------------------------------------------- agg1 + relu + gemm2 fused (R12-verbatim)
__global__ __launch_bounds__(256) void agg_gemm2_kernel(const float* __restrict__ xw,
                                                        const int* __restrict__ nbr,
                                                        const float* __restrict__ ew,
                                                        const float* __restrict__ dis,
                                                        const float* __restrict__ b,
                                                        const int* __restrict__ sid,
                                                        const float* __restrict__ w2,
                                                        float* __restrict__ xw2) {
  int wv = threadIdx.x >> 6, lane = threadIdx.x & 63;
  int i = sid[(blockIdx.x << 2) + wv];
  float di = dis[i];
  float acc = 0.0f;
#pragma unroll 4
  for (int k = 0; k < KK; ++k) {
    int s = nbr[i*KK + k];
    float coef = (dis[s] * ew[i*KK + k]) * di;   // (dis[s]*w)*dis[t]
    acc = fmaf(coef, xw[s*HH + lane], acc);
  }
  acc = fmaf(di * di, xw[i*HH + lane], acc);     // self loop last
  float hv = fmaxf(acc + b[lane], 0.0f);         // h1[i][lane]
  float acc2 = 0.0f;
#pragma unroll 16
  for (int k = 0; k < HH; ++k) {
    float hk = __shfl(hv, k, 64);
    acc2 = fmaf(hk, w2[k*HH + lane], acc2);
  }
  xw2[i*HH + lane] = acc2;
}

// ---------------------------------------------------------------- agg2 + relu + fc (final, R12-verbatim)
__global__ __launch_bounds__(256) void agg_fc_kernel(const float* __restrict__ xw,
                                                     const int* __restrict__ nbr,
                                                     const float* __restrict__ ew,
                                                     const float* __restrict__ dis,
                                                     const float* __restrict__ b,
                                                     const float* __restrict__ wfc,
                                                     const float* __restrict__ bfc,
                                                     const int* __restrict__ sid,
                                                     float* __restrict__ out) {
  int wv = threadIdx.x >> 6, lane = threadIdx.x & 63;
  int i = sid[(blockIdx.x << 2) + wv];
  float di = dis[i];
  float acc = 0.0f;
#pragma unroll 4
  for (int k = 0; k < KK; ++k) {
    int s = nbr[i*KK + k];
    float coef = (dis[s] * ew[i*KK + k]) * di;
    acc = fmaf(coef, xw[s*HH + lane], acc);
  }
  acc = fmaf(di * di, xw[i*HH + lane], acc);
  float v = fmaxf(acc + b[lane], 0.0f);             // h2 feature
  float p = v * wfc[lane];                          // h2 @ Wfc  (F_OUT = 1)
#pragma unroll
  for (int off = 32; off > 0; off >>= 1) p = p + __shfl_xor(p, off, 64);
  if (lane == 0) out[i] = p + bfc[0];
}

// ---------------------------------------------------------------- launch
extern "C" void kernel_launch(void* const* d_in, const int* in_sizes, int n_in,
                              void* d_out, int out_size, void* d_ws, size_t ws_size,
                              hipStream_t stream) {
  (void)in_sizes; (void)n_in; (void)out_size; (void)ws_size;
  const float* x   = (const float*)d_in[0];
  const float* c   = (const float*)d_in[1];
  const float* W1  = (const float*)d_in[2];
  const float* b1  = (const float*)d_in[3];
  const float* W2  = (const float*)d_in[4];
  const float* b2  = (const float*)d_in[5];
  const float* Wfc = (const float*)d_in[6];
  const float* bfc = (const float*)d_in[7];
  float* out = (float*)d_out;

  char* ws = (char*)d_ws;
  size_t off = 0;
  auto alloc = [&](size_t bytes) -> void* {
    void* p = ws + off;
    off += (bytes + 255) & ~size_t(255);
    return p;
  };
  float4*   pack   = (float4*)  alloc(NN * sizeof(float4));       // 256 KB
  float4*   sorted = (float4*)  alloc(NN * sizeof(float4));       // 256 KB
  unsigned* cnt    = (unsigned*)alloc(NCELL * sizeof(unsigned));  // 4 KB
  unsigned* cstart = (unsigned*)alloc((NCELL+1) * sizeof(unsigned));
  unsigned* cellid = (unsigned*)alloc(NN * sizeof(unsigned));     // 64 KB
  int*      sid    = (int*)     alloc(NN * sizeof(int));          // 64 KB
  int*      nbr    = (int*)     alloc(NE * sizeof(int));          // 1 MB
  float*    ew     = (float*)   alloc(NE * sizeof(float));        // 1 MB (d then ew in-place)
  float*    dis    = (float*)   alloc(NN * sizeof(float));        // 64 KB
  uint2*    part   = (uint2*)   alloc(NWAVE * sizeof(uint2));     // 8 KB wave partials
  float*    xw1    = (float*)   alloc(NN * HH * sizeof(float));   // 4 MB
  float*    xw2    = (float*)   alloc(NN * HH * sizeof(float));   // 4 MB

  const int NB = (NN + 255) / 256;
  hipMemsetAsync(cnt, 0, NCELL * sizeof(unsigned), stream);
  prep_count_kernel<<<NB,   256, 0, stream>>>(c, pack, cellid, cnt);
  scatter_kernel   <<<NB,   256, 0, stream>>>(pack, cellid, cnt, cstart, sorted, sid);
  knn_gemm1_kernel <<<KNNB + GEMM1B, 256, 0, stream>>>(sorted, cstart, c, nbr, ew, part,
                                                       x, W1, xw1);
  ewdeg_kernel     <<<NB,   256, 0, stream>>>(part, ew, dis);
  agg_gemm2_kernel <<<NN/4, 256, 0, stream>>>(xw1, nbr, ew, dis, b1, sid, W2, xw2);
  agg_fc_kernel    <<<NN/4, 256, 0, stream>>>(xw2, nbr, ew, dis, b2, Wfc, bfc, sid, out);
}